// Round 9
// baseline (188.603 us; speedup 1.0000x reference)
//
#include <hip/hip_runtime.h>

#define EPS_ 1e-6f

typedef __attribute__((ext_vector_type(8))) short bf16x8;
typedef __attribute__((ext_vector_type(4))) float f32x4;

__device__ __forceinline__ unsigned short f2b(float f){
  union { float f; unsigned int u; } v; v.f = f;
  unsigned int r = v.u + 0x7fffu + ((v.u >> 16) & 1u);
  return (unsigned short)(r >> 16);
}
__device__ __forceinline__ unsigned int packrne(float a, float b){
  return (unsigned int)f2b(a) | ((unsigned int)f2b(b) << 16);
}
__device__ __forceinline__ unsigned int packtr(float a, float b){
  return (__float_as_uint(a) >> 16) | (__float_as_uint(b) & 0xffff0000u);
}
union cvt8 { unsigned int u[4]; bf16x8 v; };

// ---------- K0: weight bf16 conversion (blocks 0..255) + style LN + K/V
//              projection via MFMA (blocks 256..271; K and V mats split) ----------
__global__ __launch_bounds__(256) void k_prep(
    const float* __restrict__ Wq, const float* __restrict__ Wk,
    const float* __restrict__ Wv, const float* __restrict__ Wo,
    const float* __restrict__ s, const float* __restrict__ lns_w,
    const float* __restrict__ lns_b,
    unsigned short* __restrict__ bWq, unsigned short* __restrict__ bWo,
    unsigned short* __restrict__ Kb, unsigned short* __restrict__ Vb){
  __shared__ unsigned short snb[64*264];
  int t = threadIdx.x;
  int blk = blockIdx.x;
  if (blk < 256){                           // Wq/Wo fp32 -> bf16, coalesced
    int i = blk*256 + t;
    bWq[i] = f2b(Wq[i]);
    bWo[i] = f2b(Wo[i]);
    return;
  }
  int idx = blk - 256;                      // 0..15
  int b = idx >> 3, n0 = ((idx >> 1) & 3) * 64, mat = idx & 1;
  int tok = t >> 2, sub = t & 3;            // 4 lanes per token
  {
    const float4* srow = (const float4*)(s + ((size_t)(b*256 + n0 + tok))*256 + sub*64);
    float4 vv[16];
    float s1 = 0.f, s2 = 0.f;
    #pragma unroll
    for (int j=0;j<16;++j){
      float4 v = srow[j]; vv[j] = v;
      s1 += (v.x+v.y)+(v.z+v.w);
      s2 += (v.x*v.x+v.y*v.y)+(v.z*v.z+v.w*v.w);
    }
    s1 += __shfl_xor(s1,1); s1 += __shfl_xor(s1,2);
    s2 += __shfl_xor(s2,1); s2 += __shfl_xor(s2,2);
    float mu = s1*(1.f/256.f);
    float rstd = rsqrtf(s2*(1.f/256.f) - mu*mu + EPS_);
    const float4* wr = (const float4*)(lns_w + sub*64);
    const float4* br = (const float4*)(lns_b + sub*64);
    #pragma unroll
    for (int j=0;j<16;++j){
      float4 v = vv[j], g = wr[j], o = br[j];
      float n0v = (v.x-mu)*rstd*g.x + o.x;
      float n1v = (v.y-mu)*rstd*g.y + o.y;
      float n2v = (v.z-mu)*rstd*g.z + o.z;
      float n3v = (v.w-mu)*rstd*g.w + o.w;
      uint2 pk = { packrne(n0v,n1v), packrne(n2v,n3v) };
      *(uint2*)&snb[tok*264 + sub*64 + j*4] = pk;
    }
  }
  __syncthreads();
  int lane = t & 63, w = t >> 6, quad = lane >> 4, l16 = lane & 15;
  const float* W = mat ? Wv : Wk;
  f32x4 acc[4][4];
  #pragma unroll
  for (int ot=0;ot<4;++ot)
    #pragma unroll
    for (int nt=0;nt<4;++nt) acc[ot][nt] = (f32x4){0.f,0.f,0.f,0.f};
  for (int ks=0; ks<8; ++ks){
    bf16x8 afr[4], bfr[4];
    #pragma unroll
    for (int ot=0;ot<4;++ot){
      const float4* wr = (const float4*)(W + (size_t)(w*64 + ot*16 + l16)*256 + ks*32 + quad*8);
      float4 a0 = wr[0], a1 = wr[1];
      cvt8 cv;
      cv.u[0]=packrne(a0.x,a0.y); cv.u[1]=packrne(a0.z,a0.w);
      cv.u[2]=packrne(a1.x,a1.y); cv.u[3]=packrne(a1.z,a1.w);
      afr[ot] = cv.v;
    }
    #pragma unroll
    for (int nt=0;nt<4;++nt)
      bfr[nt] = *(const bf16x8*)&snb[(nt*16+l16)*264 + ks*32 + quad*8];
    #pragma unroll
    for (int ot=0;ot<4;++ot)
      #pragma unroll
      for (int nt=0;nt<4;++nt)
        acc[ot][nt] = __builtin_amdgcn_mfma_f32_16x16x32_bf16(afr[ot], bfr[nt], acc[ot][nt], 0,0,0);
  }
  #pragma unroll
  for (int ot=0;ot<4;++ot){
    int otg = w*4 + ot;                     // 0..15
    int h = otg >> 1, dbase = (otg&1)*16 + quad*4;
    #pragma unroll
    for (int nt=0;nt<4;++nt){
      int n = n0 + nt*16 + l16;
      if (!mat){
        uint2 pk = { packrne(acc[ot][nt][0], acc[ot][nt][1]),
                     packrne(acc[ot][nt][2], acc[ot][nt][3]) };
        *(uint2*)&Kb[(((size_t)(b*8+h))*256 + n)*32 + dbase] = pk;
      } else {
        #pragma unroll
        for (int r=0;r<4;++r)
          Vb[(((size_t)(b*8+h))*32 + dbase + r)*256 + n] = f2b(acc[ot][nt][r]);
      }
    }
  }
}

// ---------- K1: fused LN + Qproj + attention + Wo + residual ----------
// 1024 blocks x 32 positions, 4 waves. wave = (ptile, ohalf).
// R9 changes vs R8:
//  - LN phase vectorized: thread (p4=t&7, cg=t>>3) loads 8x float4 (8 ch x
//    4 pos, 128B in flight per thread -> 32MB aggregate -> HBM-saturating,
//    vs scalar 4B loads at ~730 GB/s). Normalization done in-register
//    (deletes the old second LDS read-back pass). Reduction: 3x shfl_xor
//    in-wave (8 channel-groups) + LDS across 4 waves.
//  - Epilogue: all 32 residual x-loads hoisted into regs before the stores.
//  - __launch_bounds__(256,4): VGPR cap 128 guarantees 4 blocks/CU.
// Heads loop unchanged from R8 (streaming no-max softmax, hoisted loads,
// unroll 4, setprio around MFMA clusters, P via shfl, scale*log2e in q).
__global__ __launch_bounds__(256,4) void k_mega(
    const float* __restrict__ x, const float* __restrict__ ln_w,
    const float* __restrict__ ln_b,
    const unsigned short* __restrict__ bWq, const unsigned short* __restrict__ bWo,
    const unsigned short* __restrict__ Kb, const unsigned short* __restrict__ Vb,
    const float* __restrict__ bo, float* __restrict__ out){
  __shared__ unsigned short buf1[32*264];   // hn -> q -> att   (16896 B)
  __shared__ float st[512];                 //                  ( 2048 B)
  int t = threadIdx.x;
  int blk = blockIdx.x;                     // 0..1023
  int b = blk >> 9, p0 = (blk & 511) << 5;

  // ---- channel LN: float4 x pass, in-register normalize ----
  {
    int p4 = t & 7, cg = t >> 3;            // 8 pos-quads x 32 ch-groups(8)
    const float* xq = x + ((size_t)(b*256 + cg*8) << 14) + p0 + p4*4;
    float vr[8][4];
    #pragma unroll
    for (int j=0;j<8;++j){
      float4 v = *(const float4*)(xq + ((size_t)j << 14));
      vr[j][0]=v.x; vr[j][1]=v.y; vr[j][2]=v.z; vr[j][3]=v.w;
    }
    float s1v[4]={0.f,0.f,0.f,0.f}, s2v[4]={0.f,0.f,0.f,0.f};
    #pragma unroll
    for (int j=0;j<8;++j)
      #pragma unroll
      for (int i=0;i<4;++i){ s1v[i]+=vr[j][i]; s2v[i]+=vr[j][i]*vr[j][i]; }
    #pragma unroll
    for (int i=0;i<4;++i){
      s1v[i]+=__shfl_xor(s1v[i],8);  s2v[i]+=__shfl_xor(s2v[i],8);
      s1v[i]+=__shfl_xor(s1v[i],16); s2v[i]+=__shfl_xor(s2v[i],16);
      s1v[i]+=__shfl_xor(s1v[i],32); s2v[i]+=__shfl_xor(s2v[i],32);
    }
    int wv = t >> 6;
    if ((t & 56) == 0){                     // one lane per (wave, p4)
      #pragma unroll
      for (int i=0;i<4;++i){
        st[(wv*8 + p4)*4 + i]       = s1v[i];
        st[128 + (wv*8 + p4)*4 + i] = s2v[i];
      }
    }
    __syncthreads();
    float mu[4], rstd[4];
    #pragma unroll
    for (int i=0;i<4;++i){
      float a = st[(0*8+p4)*4+i] + st[(1*8+p4)*4+i]
              + st[(2*8+p4)*4+i] + st[(3*8+p4)*4+i];
      float q = st[128+(0*8+p4)*4+i] + st[128+(1*8+p4)*4+i]
              + st[128+(2*8+p4)*4+i] + st[128+(3*8+p4)*4+i];
      mu[i] = a*(1.f/256.f);
      rstd[i] = rsqrtf(q*(1.f/256.f) - mu[i]*mu[i] + EPS_);
    }
    float lwv[8], lbv[8];
    {
      float4 a0 = *(const float4*)(ln_w + cg*8);
      float4 a1 = *(const float4*)(ln_w + cg*8 + 4);
      float4 b0 = *(const float4*)(ln_b + cg*8);
      float4 b1 = *(const float4*)(ln_b + cg*8 + 4);
      lwv[0]=a0.x; lwv[1]=a0.y; lwv[2]=a0.z; lwv[3]=a0.w;
      lwv[4]=a1.x; lwv[5]=a1.y; lwv[6]=a1.z; lwv[7]=a1.w;
      lbv[0]=b0.x; lbv[1]=b0.y; lbv[2]=b0.z; lbv[3]=b0.w;
      lbv[4]=b1.x; lbv[5]=b1.y; lbv[6]=b1.z; lbv[7]=b1.w;
    }
    #pragma unroll
    for (int i=0;i<4;++i){
      int prow = p4*4 + i;
      float n_[8];
      #pragma unroll
      for (int j=0;j<8;++j)
        n_[j] = (vr[j][i]-mu[i])*rstd[i]*lwv[j] + lbv[j];
      uint2 w0 = { packrne(n_[0],n_[1]), packrne(n_[2],n_[3]) };
      uint2 w1 = { packrne(n_[4],n_[5]), packrne(n_[6],n_[7]) };
      *(uint2*)&buf1[prow*264 + cg*8]     = w0;
      *(uint2*)&buf1[prow*264 + cg*8 + 4] = w1;
    }
  }
  __syncthreads();                          // hn ready in buf1

  int lane = t & 63, w = t >> 6, quad = lane >> 4, l16 = lane & 15;
  int ptile = w & 1, ohalf = w >> 1;
  int prow = ptile*16 + l16;
  const float qs = 0.17677669529663689f * 1.44269504088896341f; // scale*log2e

  // ---- Q-proj: wave w -> o range [w*64, +64), both p-tiles ----
  {
    f32x4 acc[4][2];
    #pragma unroll
    for (int ot=0;ot<4;++ot)
      #pragma unroll
      for (int pt=0;pt<2;++pt) acc[ot][pt] = (f32x4){0.f,0.f,0.f,0.f};
    const unsigned short* wq = bWq + (size_t)(w*64 + l16)*256 + quad*8;
    #pragma unroll 2
    for (int ks=0; ks<8; ++ks){
      bf16x8 bfr[2], afr[4];
      #pragma unroll
      for (int ot=0;ot<4;++ot)
        afr[ot] = *(const bf16x8*)(wq + (size_t)ot*16*256 + ks*32);
      #pragma unroll
      for (int pt=0;pt<2;++pt)
        bfr[pt] = *(const bf16x8*)&buf1[(pt*16+l16)*264 + ks*32 + quad*8];
      #pragma unroll
      for (int ot=0;ot<4;++ot)
        #pragma unroll
        for (int pt=0;pt<2;++pt)
          acc[ot][pt] = __builtin_amdgcn_mfma_f32_16x16x32_bf16(afr[ot], bfr[pt], acc[ot][pt], 0,0,0);
    }
    __syncthreads();                        // all hn reads complete
    #pragma unroll
    for (int ot=0;ot<4;++ot){
      int o = w*64 + ot*16 + quad*4;
      #pragma unroll
      for (int pt=0;pt<2;++pt){
        uint2 pk = { packrne(acc[ot][pt][0]*qs, acc[ot][pt][1]*qs),
                     packrne(acc[ot][pt][2]*qs, acc[ot][pt][3]*qs) };
        *(uint2*)&buf1[(pt*16+l16)*264 + o] = pk;
      }
    }
  }
  __syncthreads();                          // q ready in buf1 [p][o]

  // ---- heads loop (barrier-free): wave handles heads ohalf*4..+4,
  //      positions ptile*16..+16. Streaming fused score->exp->P->PV per
  //      32-token chunk; sum accumulated online; 1/sum deferred. ----
  int srcA = ((( 2*quad   )&3)<<4) + l16;
  int srcB = (((2*quad + 1)&3)<<4) + l16;
  bool hiq = quad >= 2;
  bf16x8 qf[4];
  #pragma unroll
  for (int hh=0;hh<4;++hh)
    qf[hh] = *(const bf16x8*)&buf1[prow*264 + (ohalf*4+hh)*32 + quad*8];

  for (int hh=0; hh<4; ++hh){
    int h = ohalf*4 + hh;
    int bh = b*8 + h;
    const unsigned short* kb = Kb + (size_t)bh*8192 + quad*8;
    const unsigned short* vb = Vb + (size_t)bh*8192 + quad*8;
    f32x4 av[2] = {{0.f,0.f,0.f,0.f},{0.f,0.f,0.f,0.f}};
    float sm0=0.f, sm1=0.f, sm2=0.f, sm3=0.f;
    #pragma unroll 4
    for (int ks=0; ks<8; ++ks){
      bf16x8 kf0 = *(const bf16x8*)(kb + (size_t)((2*ks  )*16+l16)*32);
      bf16x8 kf1 = *(const bf16x8*)(kb + (size_t)((2*ks+1)*16+l16)*32);
      bf16x8 vf0 = *(const bf16x8*)(vb + (size_t)(     l16)*256 + ks*32);
      bf16x8 vf1 = *(const bf16x8*)(vb + (size_t)(16 + l16)*256 + ks*32);
      f32x4 z = {0.f,0.f,0.f,0.f};
      __builtin_amdgcn_s_setprio(1);
      f32x4 s0 = __builtin_amdgcn_mfma_f32_16x16x32_bf16(kf0, qf[hh], z, 0,0,0);
      f32x4 s1 = __builtin_amdgcn_mfma_f32_16x16x32_bf16(kf1, qf[hh], z, 0,0,0);
      __builtin_amdgcn_s_setprio(0);
      float e00 = exp2f(s0[0]), e01 = exp2f(s0[1]);
      float e02 = exp2f(s0[2]), e03 = exp2f(s0[3]);
      float e10 = exp2f(s1[0]), e11 = exp2f(s1[1]);
      float e12 = exp2f(s1[2]), e13 = exp2f(s1[3]);
      sm0 += e00 + e10; sm1 += e01 + e11;
      sm2 += e02 + e12; sm3 += e03 + e13;
      unsigned int p00 = packtr(e00, e01), p01 = packtr(e02, e03);
      unsigned int p10 = packtr(e10, e11), p11 = packtr(e12, e13);
      unsigned int aA0 = (unsigned int)__shfl((int)p00, srcA);
      unsigned int aB0 = (unsigned int)__shfl((int)p10, srcA);
      unsigned int aA1 = (unsigned int)__shfl((int)p01, srcA);
      unsigned int aB1 = (unsigned int)__shfl((int)p11, srcA);
      unsigned int bA0 = (unsigned int)__shfl((int)p00, srcB);
      unsigned int bB0 = (unsigned int)__shfl((int)p10, srcB);
      unsigned int bA1 = (unsigned int)__shfl((int)p01, srcB);
      unsigned int bB1 = (unsigned int)__shfl((int)p11, srcB);
      cvt8 cv;
      cv.u[0] = hiq ? aB0 : aA0;
      cv.u[1] = hiq ? aB1 : aA1;
      cv.u[2] = hiq ? bB0 : bA0;
      cv.u[3] = hiq ? bB1 : bA1;
      bf16x8 pf = cv.v;
      __builtin_amdgcn_s_setprio(1);
      av[0] = __builtin_amdgcn_mfma_f32_16x16x32_bf16(vf0, pf, av[0], 0,0,0);
      av[1] = __builtin_amdgcn_mfma_f32_16x16x32_bf16(vf1, pf, av[1], 0,0,0);
      __builtin_amdgcn_s_setprio(0);
    }
    float sm = (sm0+sm1)+(sm2+sm3);
    sm += __shfl_xor(sm, 16);
    sm += __shfl_xor(sm, 32);
    float inv = 1.f/sm;
    #pragma unroll
    for (int dt=0; dt<2; ++dt){
      uint2 pko = { packrne(av[dt][0]*inv, av[dt][1]*inv),
                    packrne(av[dt][2]*inv, av[dt][3]*inv) };
      *(uint2*)&buf1[prow*264 + h*32 + dt*16 + quad*4] = pko;
    }
  }
  __syncthreads();                          // att[32][256] complete in buf1

  // ---- Wo GEMM (K=256 from buf1) + bias + residual ----
  {
    f32x4 oacc[4][2];
    #pragma unroll
    for (int ot=0;ot<4;++ot)
      #pragma unroll
      for (int pt=0;pt<2;++pt) oacc[ot][pt] = (f32x4){0.f,0.f,0.f,0.f};
    const unsigned short* wo = bWo + (size_t)(w*64 + l16)*256 + quad*8;
    #pragma unroll 2
    for (int ks=0; ks<8; ++ks){
      bf16x8 bfr[2], afr[4];
      #pragma unroll
      for (int ot=0;ot<4;++ot)
        afr[ot] = *(const bf16x8*)(wo + (size_t)ot*16*256 + ks*32);
      #pragma unroll
      for (int pt=0;pt<2;++pt)
        bfr[pt] = *(const bf16x8*)&buf1[(pt*16+l16)*264 + ks*32 + quad*8];
      #pragma unroll
      for (int ot=0;ot<4;++ot)
        #pragma unroll
        for (int pt=0;pt<2;++pt)
          oacc[ot][pt] = __builtin_amdgcn_mfma_f32_16x16x32_bf16(afr[ot], bfr[pt], oacc[ot][pt], 0,0,0);
    }
    // hoist all residual x loads (independent; 32 outstanding 4B reads)
    float xr[4][2][4];
    #pragma unroll
    for (int ot=0;ot<4;++ot){
      int o = w*64 + ot*16 + quad*4;
      #pragma unroll
      for (int pt=0;pt<2;++pt){
        int p = p0 + pt*16 + l16;
        #pragma unroll
        for (int r=0;r<4;++r)
          xr[ot][pt][r] = x[(((size_t)b*256 + o + r) << 14) + p];
      }
    }
    #pragma unroll
    for (int ot=0;ot<4;++ot){
      int o = w*64 + ot*16 + quad*4;
      #pragma unroll
      for (int pt=0;pt<2;++pt){
        int p = p0 + pt*16 + l16;
        #pragma unroll
        for (int r=0;r<4;++r){
          size_t idx = (((size_t)b*256 + o + r) << 14) + p;
          out[idx] = oacc[ot][pt][r] + bo[o+r] + xr[ot][pt][r];
        }
      }
    }
  }
}

extern "C" void kernel_launch(void* const* d_in, const int* in_sizes, int n_in,
                              void* d_out, int out_size, void* d_ws, size_t ws_size,
                              hipStream_t stream) {
  const float* x     = (const float*)d_in[0];
  const float* s     = (const float*)d_in[1];
  const float* ln_w  = (const float*)d_in[2];
  const float* ln_b  = (const float*)d_in[3];
  const float* lns_w = (const float*)d_in[4];
  const float* lns_b = (const float*)d_in[5];
  const float* Wq    = (const float*)d_in[6];
  const float* Wk    = (const float*)d_in[7];
  const float* Wv    = (const float*)d_in[8];
  const float* Wo    = (const float*)d_in[9];
  const float* bo    = (const float*)d_in[10];
  float* out = (float*)d_out;

  unsigned short* bWq = (unsigned short*)d_ws;  //  65536 us
  unsigned short* bWo = bWq + 65536;            //  65536 us
  unsigned short* Kb  = bWo + 65536;            // 131072 us  [bh][n][d]
  unsigned short* Vb  = Kb + 131072;            // 131072 us  [bh][d][n]
  // total ws: 786 KB

  k_prep<<<272,  256, 0, stream>>>(Wq, Wk, Wv, Wo, s, lns_w, lns_b, bWq, bWo, Kb, Vb);
  k_mega<<<1024, 256, 0, stream>>>(x, ln_w, ln_b, bWq, bWo, Kb, Vb, bo, out);
}

// Round 10
// 166.946 us; speedup vs baseline: 1.1297x; 1.1297x over previous
//
#include <hip/hip_runtime.h>

#define EPS_ 1e-6f

typedef __attribute__((ext_vector_type(8))) short bf16x8;
typedef __attribute__((ext_vector_type(4))) float f32x4;
typedef __attribute__((ext_vector_type(16))) float f32x16;

__device__ __forceinline__ unsigned short f2b(float f){
  union { float f; unsigned int u; } v; v.f = f;
  unsigned int r = v.u + 0x7fffu + ((v.u >> 16) & 1u);
  return (unsigned short)(r >> 16);
}
__device__ __forceinline__ unsigned int packrne(float a, float b){
  return (unsigned int)f2b(a) | ((unsigned int)f2b(b) << 16);
}
__device__ __forceinline__ unsigned int packtr(float a, float b){
  return (__float_as_uint(a) >> 16) | (__float_as_uint(b) & 0xffff0000u);
}
union cvt8 { unsigned int u[4]; bf16x8 v; };

// ---------- K0: weight bf16 conversion (blocks 0..255) + style LN + K/V
//              projection via MFMA (blocks 256..271; K and V mats split) ----------
__global__ __launch_bounds__(256) void k_prep(
    const float* __restrict__ Wq, const float* __restrict__ Wk,
    const float* __restrict__ Wv, const float* __restrict__ Wo,
    const float* __restrict__ s, const float* __restrict__ lns_w,
    const float* __restrict__ lns_b,
    unsigned short* __restrict__ bWq, unsigned short* __restrict__ bWo,
    unsigned short* __restrict__ Kb, unsigned short* __restrict__ Vb){
  __shared__ unsigned short snb[64*264];
  int t = threadIdx.x;
  int blk = blockIdx.x;
  if (blk < 256){                           // Wq/Wo fp32 -> bf16, coalesced
    int i = blk*256 + t;
    bWq[i] = f2b(Wq[i]);
    bWo[i] = f2b(Wo[i]);
    return;
  }
  int idx = blk - 256;                      // 0..15
  int b = idx >> 3, n0 = ((idx >> 1) & 3) * 64, mat = idx & 1;
  int tok = t >> 2, sub = t & 3;            // 4 lanes per token
  {
    const float4* srow = (const float4*)(s + ((size_t)(b*256 + n0 + tok))*256 + sub*64);
    float4 vv[16];
    float s1 = 0.f, s2 = 0.f;
    #pragma unroll
    for (int j=0;j<16;++j){
      float4 v = srow[j]; vv[j] = v;
      s1 += (v.x+v.y)+(v.z+v.w);
      s2 += (v.x*v.x+v.y*v.y)+(v.z*v.z+v.w*v.w);
    }
    s1 += __shfl_xor(s1,1); s1 += __shfl_xor(s1,2);
    s2 += __shfl_xor(s2,1); s2 += __shfl_xor(s2,2);
    float mu = s1*(1.f/256.f);
    float rstd = rsqrtf(s2*(1.f/256.f) - mu*mu + EPS_);
    const float4* wr = (const float4*)(lns_w + sub*64);
    const float4* br = (const float4*)(lns_b + sub*64);
    #pragma unroll
    for (int j=0;j<16;++j){
      float4 v = vv[j], g = wr[j], o = br[j];
      float n0v = (v.x-mu)*rstd*g.x + o.x;
      float n1v = (v.y-mu)*rstd*g.y + o.y;
      float n2v = (v.z-mu)*rstd*g.z + o.z;
      float n3v = (v.w-mu)*rstd*g.w + o.w;
      uint2 pk = { packrne(n0v,n1v), packrne(n2v,n3v) };
      *(uint2*)&snb[tok*264 + sub*64 + j*4] = pk;
    }
  }
  __syncthreads();
  int lane = t & 63, w = t >> 6, quad = lane >> 4, l16 = lane & 15;
  const float* W = mat ? Wv : Wk;
  f32x4 acc[4][4];
  #pragma unroll
  for (int ot=0;ot<4;++ot)
    #pragma unroll
    for (int nt=0;nt<4;++nt) acc[ot][nt] = (f32x4){0.f,0.f,0.f,0.f};
  for (int ks=0; ks<8; ++ks){
    bf16x8 afr[4], bfr[4];
    #pragma unroll
    for (int ot=0;ot<4;++ot){
      const float4* wr = (const float4*)(W + (size_t)(w*64 + ot*16 + l16)*256 + ks*32 + quad*8);
      float4 a0 = wr[0], a1 = wr[1];
      cvt8 cv;
      cv.u[0]=packrne(a0.x,a0.y); cv.u[1]=packrne(a0.z,a0.w);
      cv.u[2]=packrne(a1.x,a1.y); cv.u[3]=packrne(a1.z,a1.w);
      afr[ot] = cv.v;
    }
    #pragma unroll
    for (int nt=0;nt<4;++nt)
      bfr[nt] = *(const bf16x8*)&snb[(nt*16+l16)*264 + ks*32 + quad*8];
    #pragma unroll
    for (int ot=0;ot<4;++ot)
      #pragma unroll
      for (int nt=0;nt<4;++nt)
        acc[ot][nt] = __builtin_amdgcn_mfma_f32_16x16x32_bf16(afr[ot], bfr[nt], acc[ot][nt], 0,0,0);
  }
  #pragma unroll
  for (int ot=0;ot<4;++ot){
    int otg = w*4 + ot;                     // 0..15
    int h = otg >> 1, dbase = (otg&1)*16 + quad*4;
    #pragma unroll
    for (int nt=0;nt<4;++nt){
      int n = n0 + nt*16 + l16;
      if (!mat){
        uint2 pk = { packrne(acc[ot][nt][0], acc[ot][nt][1]),
                     packrne(acc[ot][nt][2], acc[ot][nt][3]) };
        *(uint2*)&Kb[(((size_t)(b*8+h))*256 + n)*32 + dbase] = pk;
      } else {
        #pragma unroll
        for (int r=0;r<4;++r)
          Vb[(((size_t)(b*8+h))*32 + dbase + r)*256 + n] = f2b(acc[ot][nt][r]);
      }
    }
  }
}

// ---------- K1: fused LN + Qproj + attention + Wo + residual ----------
// 1024 blocks x 32 positions, 4 waves. R10: heads loop rebuilt on 32x32x16
// MFMA. Wave w owns heads {2w, 2w+1} x all 32 positions:
//  - 16 chunk-chains per wave (was 32); each chunk = 32 tokens.
//  - P-transpose: 4 shfl_xor(.,32) per chunk (was 8 ds_bpermute) because the
//    32x32 C/D layout (col=lane&31, row=(reg&3)+8(reg>>2)+4(lane>>5)) keeps
//    the column local; only the lane>>5 halves exchange.
//  - heads {2w,2w+1} == the q-columns wave w wrote in Qproj -> same-wave LDS
//    handoff, post-q-write barrier deleted (4 barriers total).
// Streaming no-max softmax (|score| ~< 1 at this scale), scale*log2e in q.
// LN phase = R9 float4 vectorized, in-register normalize. Epilogue hoisted.
__global__ __launch_bounds__(256,4) void k_mega(
    const float* __restrict__ x, const float* __restrict__ ln_w,
    const float* __restrict__ ln_b,
    const unsigned short* __restrict__ bWq, const unsigned short* __restrict__ bWo,
    const unsigned short* __restrict__ Kb, const unsigned short* __restrict__ Vb,
    const float* __restrict__ bo, float* __restrict__ out){
  __shared__ unsigned short buf1[32*264];   // hn -> q -> att   (16896 B)
  __shared__ float st[512];                 //                  ( 2048 B)
  int t = threadIdx.x;
  int blk = blockIdx.x;                     // 0..1023
  int b = blk >> 9, p0 = (blk & 511) << 5;

  // ---- channel LN: float4 x pass, in-register normalize ----
  {
    int p4 = t & 7, cg = t >> 3;            // 8 pos-quads x 32 ch-groups(8)
    const float* xq = x + ((size_t)(b*256 + cg*8) << 14) + p0 + p4*4;
    float vr[8][4];
    #pragma unroll
    for (int j=0;j<8;++j){
      float4 v = *(const float4*)(xq + ((size_t)j << 14));
      vr[j][0]=v.x; vr[j][1]=v.y; vr[j][2]=v.z; vr[j][3]=v.w;
    }
    float s1v[4]={0.f,0.f,0.f,0.f}, s2v[4]={0.f,0.f,0.f,0.f};
    #pragma unroll
    for (int j=0;j<8;++j)
      #pragma unroll
      for (int i=0;i<4;++i){ s1v[i]+=vr[j][i]; s2v[i]+=vr[j][i]*vr[j][i]; }
    #pragma unroll
    for (int i=0;i<4;++i){
      s1v[i]+=__shfl_xor(s1v[i],8);  s2v[i]+=__shfl_xor(s2v[i],8);
      s1v[i]+=__shfl_xor(s1v[i],16); s2v[i]+=__shfl_xor(s2v[i],16);
      s1v[i]+=__shfl_xor(s1v[i],32); s2v[i]+=__shfl_xor(s2v[i],32);
    }
    int wv = t >> 6;
    if ((t & 56) == 0){                     // one lane per (wave, p4)
      #pragma unroll
      for (int i=0;i<4;++i){
        st[(wv*8 + p4)*4 + i]       = s1v[i];
        st[128 + (wv*8 + p4)*4 + i] = s2v[i];
      }
    }
    __syncthreads();
    float mu[4], rstd[4];
    #pragma unroll
    for (int i=0;i<4;++i){
      float a = st[(0*8+p4)*4+i] + st[(1*8+p4)*4+i]
              + st[(2*8+p4)*4+i] + st[(3*8+p4)*4+i];
      float q = st[128+(0*8+p4)*4+i] + st[128+(1*8+p4)*4+i]
              + st[128+(2*8+p4)*4+i] + st[128+(3*8+p4)*4+i];
      mu[i] = a*(1.f/256.f);
      rstd[i] = rsqrtf(q*(1.f/256.f) - mu[i]*mu[i] + EPS_);
    }
    float lwv[8], lbv[8];
    {
      float4 a0 = *(const float4*)(ln_w + cg*8);
      float4 a1 = *(const float4*)(ln_w + cg*8 + 4);
      float4 b0 = *(const float4*)(ln_b + cg*8);
      float4 b1 = *(const float4*)(ln_b + cg*8 + 4);
      lwv[0]=a0.x; lwv[1]=a0.y; lwv[2]=a0.z; lwv[3]=a0.w;
      lwv[4]=a1.x; lwv[5]=a1.y; lwv[6]=a1.z; lwv[7]=a1.w;
      lbv[0]=b0.x; lbv[1]=b0.y; lbv[2]=b0.z; lbv[3]=b0.w;
      lbv[4]=b1.x; lbv[5]=b1.y; lbv[6]=b1.z; lbv[7]=b1.w;
    }
    #pragma unroll
    for (int i=0;i<4;++i){
      int prow = p4*4 + i;
      float n_[8];
      #pragma unroll
      for (int j=0;j<8;++j)
        n_[j] = (vr[j][i]-mu[i])*rstd[i]*lwv[j] + lbv[j];
      uint2 w0 = { packrne(n_[0],n_[1]), packrne(n_[2],n_[3]) };
      uint2 w1 = { packrne(n_[4],n_[5]), packrne(n_[6],n_[7]) };
      *(uint2*)&buf1[prow*264 + cg*8]     = w0;
      *(uint2*)&buf1[prow*264 + cg*8 + 4] = w1;
    }
  }
  __syncthreads();                          // hn ready in buf1

  int lane = t & 63, w = t >> 6, quad = lane >> 4, l16 = lane & 15;
  const float qs = 0.17677669529663689f * 1.44269504088896341f; // scale*log2e

  // ---- Q-proj: wave w -> o range [w*64, +64), both p-tiles ----
  {
    f32x4 acc[4][2];
    #pragma unroll
    for (int ot=0;ot<4;++ot)
      #pragma unroll
      for (int pt=0;pt<2;++pt) acc[ot][pt] = (f32x4){0.f,0.f,0.f,0.f};
    const unsigned short* wq = bWq + (size_t)(w*64 + l16)*256 + quad*8;
    #pragma unroll 2
    for (int ks=0; ks<8; ++ks){
      bf16x8 bfr[2], afr[4];
      #pragma unroll
      for (int ot=0;ot<4;++ot)
        afr[ot] = *(const bf16x8*)(wq + (size_t)ot*16*256 + ks*32);
      #pragma unroll
      for (int pt=0;pt<2;++pt)
        bfr[pt] = *(const bf16x8*)&buf1[(pt*16+l16)*264 + ks*32 + quad*8];
      #pragma unroll
      for (int ot=0;ot<4;++ot)
        #pragma unroll
        for (int pt=0;pt<2;++pt)
          acc[ot][pt] = __builtin_amdgcn_mfma_f32_16x16x32_bf16(afr[ot], bfr[pt], acc[ot][pt], 0,0,0);
    }
    __syncthreads();                        // all hn reads complete
    #pragma unroll
    for (int ot=0;ot<4;++ot){
      int o = w*64 + ot*16 + quad*4;
      #pragma unroll
      for (int pt=0;pt<2;++pt){
        uint2 pk = { packrne(acc[ot][pt][0]*qs, acc[ot][pt][1]*qs),
                     packrne(acc[ot][pt][2]*qs, acc[ot][pt][3]*qs) };
        *(uint2*)&buf1[(pt*16+l16)*264 + o] = pk;
      }
    }
  }
  // NO barrier: wave w consumes exactly the q columns [w*64,+64) it wrote
  // (heads {2w,2w+1} = cols 64w..64w+63), same-wave LDS handoff.

  // ---- heads loop: wave w -> heads {2w, 2w+1}, all 32 positions.
  //      32x32x16 MFMA; 8 chunks of 32 tokens per head. Streaming
  //      score->exp->P->PV; sums online; 1/sum deferred. ----
  int r32 = lane & 31;
  int h5  = lane >> 5;                      // 0 or 1 (runtime; ternaries only)
  bool hb = h5 != 0;

  #pragma unroll
  for (int hh=0; hh<2; ++hh){
    int head = w*2 + hh;
    int bh = b*8 + head;
    const unsigned short* kb = Kb + (size_t)bh*8192 + (size_t)r32*32  + 8*h5;
    const unsigned short* vb = Vb + (size_t)bh*8192 + (size_t)r32*256 + 8*h5;
    const unsigned short* qrow = &buf1[r32*264 + head*32 + 8*h5];
    bf16x8 qf0 = *(const bf16x8*)(qrow);       // d 0..15 slice
    bf16x8 qf1 = *(const bf16x8*)(qrow + 16);  // d 16..31 slice
    f32x16 av;
    #pragma unroll
    for (int i=0;i<16;++i) av[i] = 0.f;
    float sm = 0.f;
    #pragma unroll 2
    for (int nc=0; nc<8; ++nc){
      bf16x8 kf0 = *(const bf16x8*)(kb + nc*1024);        // rows n, d 0..15
      bf16x8 kf1 = *(const bf16x8*)(kb + nc*1024 + 16);   // rows n, d 16..31
      bf16x8 vf0 = *(const bf16x8*)(vb + nc*32);          // k = n 0..15 of chunk
      bf16x8 vf1 = *(const bf16x8*)(vb + nc*32 + 16);     // k = n 16..31
      f32x16 sc;
      #pragma unroll
      for (int i=0;i<16;++i) sc[i] = 0.f;
      __builtin_amdgcn_s_setprio(1);
      sc = __builtin_amdgcn_mfma_f32_32x32x16_bf16(kf0, qf0, sc, 0,0,0);
      sc = __builtin_amdgcn_mfma_f32_32x32x16_bf16(kf1, qf1, sc, 0,0,0);
      __builtin_amdgcn_s_setprio(0);
      // ---- m=0 half: regs 0..7 = chunk-n 0..15 ----
      float e0 = exp2f(sc[0]), e1 = exp2f(sc[1]), e2 = exp2f(sc[2]), e3 = exp2f(sc[3]);
      float e4 = exp2f(sc[4]), e5 = exp2f(sc[5]), e6 = exp2f(sc[6]), e7 = exp2f(sc[7]);
      sm += ((e0+e1)+(e2+e3)) + ((e4+e5)+(e6+e7));
      unsigned int k0 = packtr(e0,e1), k1 = packtr(e2,e3);
      unsigned int k2 = packtr(e4,e5), k3 = packtr(e6,e7);
      unsigned int sA = hb ? k0 : k2, sB = hb ? k1 : k3;
      unsigned int rA = (unsigned int)__shfl_xor((int)sA, 32);
      unsigned int rB = (unsigned int)__shfl_xor((int)sB, 32);
      cvt8 c0;
      c0.u[0] = hb ? rA : k0;
      c0.u[1] = hb ? rB : k1;
      c0.u[2] = hb ? k2 : rA;
      c0.u[3] = hb ? k3 : rB;
      __builtin_amdgcn_s_setprio(1);
      av = __builtin_amdgcn_mfma_f32_32x32x16_bf16(vf0, c0.v, av, 0,0,0);
      __builtin_amdgcn_s_setprio(0);
      // ---- m=1 half: regs 8..15 = chunk-n 16..31 ----
      float e8  = exp2f(sc[8]),  e9  = exp2f(sc[9]),  e10 = exp2f(sc[10]), e11 = exp2f(sc[11]);
      float e12 = exp2f(sc[12]), e13 = exp2f(sc[13]), e14 = exp2f(sc[14]), e15 = exp2f(sc[15]);
      sm += ((e8+e9)+(e10+e11)) + ((e12+e13)+(e14+e15));
      unsigned int k4 = packtr(e8,e9),   k5 = packtr(e10,e11);
      unsigned int k6 = packtr(e12,e13), k7 = packtr(e14,e15);
      unsigned int sC = hb ? k4 : k6, sD = hb ? k5 : k7;
      unsigned int rC = (unsigned int)__shfl_xor((int)sC, 32);
      unsigned int rD = (unsigned int)__shfl_xor((int)sD, 32);
      cvt8 c1;
      c1.u[0] = hb ? rC : k4;
      c1.u[1] = hb ? rD : k5;
      c1.u[2] = hb ? k6 : rC;
      c1.u[3] = hb ? k7 : rD;
      __builtin_amdgcn_s_setprio(1);
      av = __builtin_amdgcn_mfma_f32_32x32x16_bf16(vf1, c1.v, av, 0,0,0);
      __builtin_amdgcn_s_setprio(0);
    }
    sm += __shfl_xor(sm, 32);
    float inv = 1.f/sm;
    // store att: lane holds col p=r32, rows d = (r&3)+8*(r>>2)+4*h5
    #pragma unroll
    for (int g=0; g<4; ++g){
      uint2 pko = { packrne(av[4*g]*inv,   av[4*g+1]*inv),
                    packrne(av[4*g+2]*inv, av[4*g+3]*inv) };
      *(uint2*)&buf1[r32*264 + head*32 + 8*g + 4*h5] = pko;
    }
  }
  __syncthreads();                          // att[32][256] complete in buf1

  // ---- Wo GEMM (K=256 from buf1) + bias + residual ----
  {
    f32x4 oacc[4][2];
    #pragma unroll
    for (int ot=0;ot<4;++ot)
      #pragma unroll
      for (int pt=0;pt<2;++pt) oacc[ot][pt] = (f32x4){0.f,0.f,0.f,0.f};
    const unsigned short* wo = bWo + (size_t)(w*64 + l16)*256 + quad*8;
    #pragma unroll 2
    for (int ks=0; ks<8; ++ks){
      bf16x8 bfr[2], afr[4];
      #pragma unroll
      for (int ot=0;ot<4;++ot)
        afr[ot] = *(const bf16x8*)(wo + (size_t)ot*16*256 + ks*32);
      #pragma unroll
      for (int pt=0;pt<2;++pt)
        bfr[pt] = *(const bf16x8*)&buf1[(pt*16+l16)*264 + ks*32 + quad*8];
      #pragma unroll
      for (int ot=0;ot<4;++ot)
        #pragma unroll
        for (int pt=0;pt<2;++pt)
          oacc[ot][pt] = __builtin_amdgcn_mfma_f32_16x16x32_bf16(afr[ot], bfr[pt], oacc[ot][pt], 0,0,0);
    }
    // hoist all residual x loads (independent; 32 outstanding 4B reads)
    float xr[4][2][4];
    #pragma unroll
    for (int ot=0;ot<4;++ot){
      int o = w*64 + ot*16 + quad*4;
      #pragma unroll
      for (int pt=0;pt<2;++pt){
        int p = p0 + pt*16 + l16;
        #pragma unroll
        for (int r=0;r<4;++r)
          xr[ot][pt][r] = x[(((size_t)b*256 + o + r) << 14) + p];
      }
    }
    #pragma unroll
    for (int ot=0;ot<4;++ot){
      int o = w*64 + ot*16 + quad*4;
      #pragma unroll
      for (int pt=0;pt<2;++pt){
        int p = p0 + pt*16 + l16;
        #pragma unroll
        for (int r=0;r<4;++r){
          size_t idx = (((size_t)b*256 + o + r) << 14) + p;
          out[idx] = oacc[ot][pt][r] + bo[o+r] + xr[ot][pt][r];
        }
      }
    }
  }
}

extern "C" void kernel_launch(void* const* d_in, const int* in_sizes, int n_in,
                              void* d_out, int out_size, void* d_ws, size_t ws_size,
                              hipStream_t stream) {
  const float* x     = (const float*)d_in[0];
  const float* s     = (const float*)d_in[1];
  const float* ln_w  = (const float*)d_in[2];
  const float* ln_b  = (const float*)d_in[3];
  const float* lns_w = (const float*)d_in[4];
  const float* lns_b = (const float*)d_in[5];
  const float* Wq    = (const float*)d_in[6];
  const float* Wk    = (const float*)d_in[7];
  const float* Wv    = (const float*)d_in[8];
  const float* Wo    = (const float*)d_in[9];
  const float* bo    = (const float*)d_in[10];
  float* out = (float*)d_out;

  unsigned short* bWq = (unsigned short*)d_ws;  //  65536 us
  unsigned short* bWo = bWq + 65536;            //  65536 us
  unsigned short* Kb  = bWo + 65536;            // 131072 us  [bh][n][d]
  unsigned short* Vb  = Kb + 131072;            // 131072 us  [bh][d][n]
  // total ws: 786 KB

  k_prep<<<272,  256, 0, stream>>>(Wq, Wk, Wv, Wo, s, lns_w, lns_b, bWq, bWo, Kb, Vb);
  k_mega<<<1024, 256, 0, stream>>>(x, ln_w, ln_b, bWq, bWo, Kb, Vb, bo, out);
}